// Round 1
// baseline (190.338 us; speedup 1.0000x reference)
//
#include <hip/hip_runtime.h>
#include <math.h>

#define LAMBDA_DAG 0.5f

// -------- Kernel 1: probs (transposed) + BCE per-block partial sums --------
__global__ void k_probs_bce(const float* __restrict__ logits,
                            const float* __restrict__ labels,
                            float* __restrict__ pT,        // [C*B] transposed probs
                            float* __restrict__ bce_part,  // [gridDim.x]
                            int B, int C) {
    const int N = B * C;
    float acc = 0.f;
    for (int idx = blockIdx.x * blockDim.x + threadIdx.x; idx < N;
         idx += gridDim.x * blockDim.x) {
        float l = logits[idx];
        float y = labels[idx];
        // logaddexp(0, l) = max(l,0) + log1p(exp(-|l|))
        acc += fmaxf(l, 0.f) + log1pf(expf(-fabsf(l))) - l * y;
        float p = 1.f / (1.f + expf(-l));
        int b = idx / C;
        int c = idx - b * C;
        pT[(size_t)c * B + b] = p;
    }
    __shared__ float sdata[256];
    sdata[threadIdx.x] = acc;
    __syncthreads();
    for (int s = blockDim.x >> 1; s > 0; s >>= 1) {
        if (threadIdx.x < s) sdata[threadIdx.x] += sdata[threadIdx.x + s];
        __syncthreads();
    }
    if (threadIdx.x == 0) bce_part[blockIdx.x] = sdata[0];
}

// -------- Kernel 2: one block per child row i; scan dag row, sum violations ----
__global__ void __launch_bounds__(256) k_dag_rows(
        const float* __restrict__ dag,   // [C*C], row i = parents of i
        const float* __restrict__ pT,    // [C*B]
        float* __restrict__ per_term,    // [C]
        float* __restrict__ npar,        // [C]
        int B, int C) {
    const int i = blockIdx.x;
    __shared__ float pi[128];            // B <= 128 (actual B = 64)
    for (int b = threadIdx.x; b < B; b += blockDim.x)
        pi[b] = pT[(size_t)i * B + b];
    __syncthreads();

    const float* drow = dag + (size_t)i * C;
    const int C4 = C >> 2;
    float psum = 0.f, pcnt = 0.f;

    const float4* drow4 = (const float4*)drow;
    for (int q = threadIdx.x; q < C4; q += blockDim.x) {
        float4 d4 = drow4[q];
        float dv[4] = {d4.x, d4.y, d4.z, d4.w};
#pragma unroll
        for (int k = 0; k < 4; ++k) {
            if (dv[k] > 0.f) {
                const int j = q * 4 + k;
                const float* pj = pT + (size_t)j * B;
                float s = 0.f;
                for (int b = 0; b < B; ++b) {
                    float diff = fmaxf(pi[b] - pj[b], 0.f);
                    s += diff * diff;
                }
                psum += s;
                pcnt += 1.f;
            }
        }
    }
    // remainder (C % 4), C=5000 is divisible by 4 but stay general
    for (int j = C4 * 4 + threadIdx.x; j < C; j += blockDim.x) {
        if (drow[j] > 0.f) {
            const float* pj = pT + (size_t)j * B;
            float s = 0.f;
            for (int b = 0; b < B; ++b) {
                float diff = fmaxf(pi[b] - pj[b], 0.f);
                s += diff * diff;
            }
            psum += s;
            pcnt += 1.f;
        }
    }

    __shared__ float s1[256], s2[256];
    s1[threadIdx.x] = psum;
    s2[threadIdx.x] = pcnt;
    __syncthreads();
    for (int s = blockDim.x >> 1; s > 0; s >>= 1) {
        if (threadIdx.x < s) {
            s1[threadIdx.x] += s1[threadIdx.x + s];
            s2[threadIdx.x] += s2[threadIdx.x + s];
        }
        __syncthreads();
    }
    if (threadIdx.x == 0) {
        per_term[i] = s1[0];
        npar[i] = s2[0];
    }
}

// -------- Kernel 3: final scalar reduction --------
__global__ void k_final(const float* __restrict__ per_term,
                        const float* __restrict__ npar,
                        const float* __restrict__ bce_part, int nb,
                        float* __restrict__ out, int B, int C) {
    float bs = 0.f, ps = 0.f, es = 0.f;
    for (int k = threadIdx.x; k < nb; k += blockDim.x) bs += bce_part[k];
    for (int i = threadIdx.x; i < C; i += blockDim.x) {
        float np = npar[i];
        es += np;
        if (np > 0.f) ps += per_term[i] / ((float)B * np);
    }
    __shared__ float s1[256], s2[256], s3[256];
    s1[threadIdx.x] = bs;
    s2[threadIdx.x] = ps;
    s3[threadIdx.x] = es;
    __syncthreads();
    for (int s = blockDim.x >> 1; s > 0; s >>= 1) {
        if (threadIdx.x < s) {
            s1[threadIdx.x] += s1[threadIdx.x + s];
            s2[threadIdx.x] += s2[threadIdx.x + s];
            s3[threadIdx.x] += s3[threadIdx.x + s];
        }
        __syncthreads();
    }
    if (threadIdx.x == 0) {
        float penalty = (s3[0] > 0.f) ? (s2[0] / s3[0]) : 0.f;
        out[0] = s1[0] / (float)(B * C) + LAMBDA_DAG * penalty;
    }
}

extern "C" void kernel_launch(void* const* d_in, const int* in_sizes, int n_in,
                              void* d_out, int out_size, void* d_ws, size_t ws_size,
                              hipStream_t stream) {
    const float* logits = (const float*)d_in[0];
    const float* labels = (const float*)d_in[1];
    const float* dag    = (const float*)d_in[2];
    float* out = (float*)d_out;

    const int C = (int)(sqrt((double)in_sizes[2]) + 0.5);
    const int B = in_sizes[0] / C;

    float* ws       = (float*)d_ws;
    float* pT       = ws;                          // C*B floats
    float* per_term = pT + (size_t)C * B;          // C floats
    float* nparw    = per_term + C;                // C floats
    float* bce_part = nparw + C;                   // NB1 floats

    const int NB1 = 320;
    k_probs_bce<<<NB1, 256, 0, stream>>>(logits, labels, pT, bce_part, B, C);
    k_dag_rows<<<C, 256, 0, stream>>>(dag, pT, per_term, nparw, B, C);
    k_final<<<1, 256, 0, stream>>>(per_term, nparw, bce_part, NB1, out, B, C);
}